// Round 2
// baseline (655.409 us; speedup 1.0000x reference)
//
#include <hip/hip_runtime.h>
#include <hip/hip_bf16.h>

#define B_ 2048
#define D_ 512
#define N_ 100000
#define F_ 64
#define NEGV (-1000000.0f)

#define NKT 16        // K tiles of 32: 512/32
#define MT 16         // 2048/128 m-tiles
#define NT 391        // ceil(100000/256) n-tiles
#define GRID (MT * NT)   // 6256 = 8 * 782 (XCD-divisible)

typedef __bf16 bfx8 __attribute__((ext_vector_type(8)));
typedef float f32x4 __attribute__((ext_vector_type(4)));
typedef unsigned short u16x8 __attribute__((ext_vector_type(8)));

static __device__ __forceinline__ unsigned short f2bf(float f) {
  unsigned u = __float_as_uint(f);
  unsigned r = (u + 0x7fffu + ((u >> 16) & 1u)) >> 16;
  return (unsigned short)r;
}
static __device__ __forceinline__ float bf2f(unsigned short u) {
  return __uint_as_float(((unsigned)u) << 16);
}

static __device__ __forceinline__ void async_copy16(const void* g, void* l) {
  __builtin_amdgcn_global_load_lds((const __attribute__((address_space(1))) void*)g,
                                   (__attribute__((address_space(3))) void*)l, 16, 0, 0);
}

// ---- targets (fp32, matches reference einsum) + out init + q->bf16 ---------
__global__ void targets_convert(const float* __restrict__ q, const float* __restrict__ rhs,
                                const int* __restrict__ queries, float* __restrict__ targets,
                                float* __restrict__ out, unsigned short* __restrict__ qb) {
  __shared__ float wsum[4];
  int b = blockIdx.x;
  int tid = threadIdx.x, lane = tid & 63, w = tid >> 6;
  int p = queries[b * 3 + 2];
  float2 v = ((const float2*)(q + (size_t)b * D_))[tid];   // 256 x 2 = 512 elems
  ushort2 o; o.x = f2bf(v.x); o.y = f2bf(v.y);
  ((ushort2*)(qb + (size_t)b * D_))[tid] = o;
  float s = v.x * rhs[(size_t)(2 * tid) * N_ + p] + v.y * rhs[(size_t)(2 * tid + 1) * N_ + p];
  for (int off = 32; off; off >>= 1) s += __shfl_down(s, off, 64);
  if (lane == 0) wsum[w] = s;
  __syncthreads();
  if (tid == 0) {
    targets[b] = wsum[0] + wsum[1] + wsum[2] + wsum[3];
    out[b] = 1.0f;
  }
}

// ---- rhs (D x N fp32) -> rt (N x D bf16), 64x64 LDS tile transpose ---------
__global__ void transpose_rhs(const float* __restrict__ rhs, unsigned short* __restrict__ rt) {
  __shared__ float tile[64][65];
  int n0 = blockIdx.x * 64, d0 = blockIdx.y * 64;
  int tid = threadIdx.x;
  if (n0 + 64 <= N_) {
#pragma unroll
    for (int p = 0; p < 4; ++p) {
      int e = p * 256 + tid;
      int d = e >> 4, c4 = e & 15;
      float4 v = *(const float4*)(rhs + (size_t)(d0 + d) * N_ + n0 + c4 * 4);
      tile[d][c4 * 4 + 0] = v.x; tile[d][c4 * 4 + 1] = v.y;
      tile[d][c4 * 4 + 2] = v.z; tile[d][c4 * 4 + 3] = v.w;
    }
  } else {
    int c = tid & 63, r4 = tid >> 6;
#pragma unroll
    for (int p = 0; p < 16; ++p) {
      int d = r4 + p * 4;
      if (n0 + c < N_) tile[d][c] = rhs[(size_t)(d0 + d) * N_ + n0 + c];
    }
  }
  __syncthreads();
#pragma unroll
  for (int p = 0; p < 4; ++p) {
    int e = p * 256 + tid;
    int n = e >> 4, dg = e & 15;
    if (n0 + n < N_) {
      ushort4 o;
      o.x = f2bf(tile[dg * 4 + 0][n]);
      o.y = f2bf(tile[dg * 4 + 1][n]);
      o.z = f2bf(tile[dg * 4 + 2][n]);
      o.w = f2bf(tile[dg * 4 + 3][n]);
      *(ushort4*)(rt + (size_t)(n0 + n) * D_ + d0 + dg * 4) = o;
    }
  }
}

// ---- main GEMM: 128x256 block, 4 waves (wave=128x64), BK=32 ----------------
// Structure: free-running 2-blocks/CU + triple-buffered LDS with 2-tile
// staging lookahead -> per-iter wait is s_waitcnt vmcnt(6) (tile kt landed,
// tile kt+1's 6 loads still fly), never a drain until the final iter.
// LDS swizzle (zero-conflict, proven r1): 16B granule slot = quad ^ ((row>>1)&3),
// staged via pre-swizzled GLOBAL source + linear LDS dest (m104/m173 rule).
// Per wave-tile: 12 ds_read_b128 / 32 MFMA = 375 B/MFMA (old kernel: 500 + 8-way).
__global__ void __launch_bounds__(256, 2) gemm_count(
    const unsigned short* __restrict__ qb,   // B x D bf16
    const unsigned short* __restrict__ rt,   // N x D bf16 (transposed rhs)
    const float* __restrict__ targets,
    float* __restrict__ out) {
  __shared__ __align__(128) unsigned short As[3 * 4096];   // 3 x 8 KB  (128x32)
  __shared__ __align__(128) unsigned short Bs[3 * 8192];   // 3 x 16 KB (256x32)
  __shared__ float sT[128];
  __shared__ int cnt2[4][128];

  int tid = threadIdx.x;
  int orig = blockIdx.x;
  // bijective XCD chunking: 6256 = 8 * 782; consecutive lin within an XCD
  // share n-panels (B) and the whole 2MB qb stays L2-hot.
  int lin = (orig & 7) * (GRID / 8) + (orig >> 3);
  int m0 = (lin & (MT - 1)) * 128;
  int n0 = (lin / MT) * 256;

  if (tid < 128) sT[tid] = targets[m0 + tid];

  int w = tid >> 6, lane = tid & 63;
  int quad = lane >> 4, l16 = lane & 15;
  int nw = w * 64;                        // wave's 64-col quarter of the 256 N
  int xq = quad ^ ((l16 >> 1) & 3);       // swizzled 16B-slot within a row

  // staging: LDS dest linear (unit = tid per 4KB call); source pre-swizzled:
  // phys unit p holds logical col ((p&3)^((p>>3)&3)) of row p>>2
  int srow = tid >> 2;
  int scol = ((tid & 3) ^ ((tid >> 3) & 3)) * 8;
  const unsigned short* aC0 = qb + (size_t)(m0 + srow) * D_ + scol;
  const unsigned short* aC1 = qb + (size_t)(m0 + 64 + srow) * D_ + scol;
  int gn0 = n0 + srow;        if (gn0 > N_ - 1) gn0 = N_ - 1;
  int gn1 = n0 + 64 + srow;   if (gn1 > N_ - 1) gn1 = N_ - 1;
  int gn2 = n0 + 128 + srow;  if (gn2 > N_ - 1) gn2 = N_ - 1;
  int gn3 = n0 + 192 + srow;  if (gn3 > N_ - 1) gn3 = N_ - 1;
  const unsigned short* bC0 = rt + (size_t)gn0 * D_ + scol;
  const unsigned short* bC1 = rt + (size_t)gn1 * D_ + scol;
  const unsigned short* bC2 = rt + (size_t)gn2 * D_ + scol;
  const unsigned short* bC3 = rt + (size_t)gn3 * D_ + scol;

#define STAGE(K, SB)                                                       \
  do {                                                                     \
    int ko = (K) * 32;                                                     \
    async_copy16(aC0 + ko, &As[(SB) * 4096 + tid * 8]);                    \
    async_copy16(aC1 + ko, &As[(SB) * 4096 + (256 + tid) * 8]);            \
    async_copy16(bC0 + ko, &Bs[(SB) * 8192 + tid * 8]);                    \
    async_copy16(bC1 + ko, &Bs[(SB) * 8192 + (256 + tid) * 8]);            \
    async_copy16(bC2 + ko, &Bs[(SB) * 8192 + (512 + tid) * 8]);            \
    async_copy16(bC3 + ko, &Bs[(SB) * 8192 + (768 + tid) * 8]);            \
  } while (0)

  f32x4 acc[8][4];
  f32x4 z = {0.f, 0.f, 0.f, 0.f};
#pragma unroll
  for (int mi = 0; mi < 8; ++mi)
#pragma unroll
    for (int ni = 0; ni < 4; ++ni) acc[mi][ni] = z;

  // prologue: tiles 0 and 1 in flight (12 loads)
  STAGE(0, 0);
  STAGE(1, 1);

  int cur = 0, s2 = 2;
  for (int kt = 0; kt < NKT; ++kt) {
    // all waves past last iter's ds_reads before this iter's stage can land
    asm volatile("s_waitcnt lgkmcnt(0)" ::: "memory");
    __builtin_amdgcn_s_barrier();
    // tile kt's 6 loads retired; tile kt+1's 6 newest may keep flying
    if (kt == NKT - 1) { asm volatile("s_waitcnt vmcnt(0)" ::: "memory"); }
    else               { asm volatile("s_waitcnt vmcnt(6)" ::: "memory"); }
    if (kt + 2 < NKT) STAGE(kt + 2, s2);   // issue early; lands >= 1 iter later

    const unsigned short* Ab = &As[cur * 4096];
    const unsigned short* Bb = &Bs[cur * 8192];
    bfx8 af[8], bf[4];
#pragma unroll
    for (int mi = 0; mi < 8; ++mi) {
      int m = mi * 16 + l16;
      af[mi] = __builtin_bit_cast(bfx8, *(const u16x8*)&Ab[m * 32 + xq * 8]);
    }
#pragma unroll
    for (int ni = 0; ni < 4; ++ni) {
      int n = nw + ni * 16 + l16;
      bf[ni] = __builtin_bit_cast(bfx8, *(const u16x8*)&Bb[n * 32 + xq * 8]);
    }
#pragma unroll
    for (int mi = 0; mi < 8; ++mi)
#pragma unroll
      for (int ni = 0; ni < 4; ++ni)
        acc[mi][ni] = __builtin_amdgcn_mfma_f32_16x16x32_bf16(af[mi], bf[ni], acc[mi][ni], 0, 0, 0);

    cur = (cur == 2) ? 0 : cur + 1;
    s2 = (s2 == 2) ? 0 : s2 + 1;
  }
#undef STAGE

  // epilogue: compare vs target, reduce across l16, combine across waves
#pragma unroll
  for (int mi = 0; mi < 8; ++mi) {
#pragma unroll
    for (int reg = 0; reg < 4; ++reg) {
      int rl = mi * 16 + quad * 4 + reg;      // C/D: row=(lane>>4)*4+reg
      float t = sT[rl];
      int c = 0;
#pragma unroll
      for (int ni = 0; ni < 4; ++ni) {
        int col = n0 + nw + ni * 16 + l16;    // C/D: col=lane&15
        if (col < N_ && acc[mi][ni][reg] >= t) c++;
      }
      c += __shfl_xor(c, 1, 64);
      c += __shfl_xor(c, 2, 64);
      c += __shfl_xor(c, 4, 64);
      c += __shfl_xor(c, 8, 64);
      if (l16 == 0) cnt2[w][rl] = c;          // each slot written exactly once
    }
  }
  __syncthreads();
  if (tid < 128) {
    int tot = cnt2[0][tid] + cnt2[1][tid] + cnt2[2][tid] + cnt2[3][tid];
    if (tot) atomicAdd(&out[m0 + tid], (float)tot);
  }
}

// ---- corrections: wave-cooperative dots over filter ∪ {true}, 8 waves ------
__global__ void corrections(const unsigned short* __restrict__ qb,
                            const unsigned short* __restrict__ rt,
                            const int* __restrict__ queries,
                            const int* __restrict__ filt,
                            const float* __restrict__ targets,
                            float* __restrict__ out) {
  int b = blockIdx.x;
  int tid = threadIdx.x;  // 512
  int w = tid >> 6, lane = tid & 63;
  __shared__ int idx[F_ + 1];
  __shared__ unsigned char uq[F_ + 1];
  if (tid <= F_) idx[tid] = (tid < F_) ? filt[b * F_ + tid] : queries[b * 3 + 2];
  __syncthreads();
  if (tid <= F_) {
    int p = idx[tid];
    bool u = true;
    for (int j = 0; j < tid; ++j)
      if (idx[j] == p) u = false;
    uq[tid] = u;
  }
  __syncthreads();
  float t = targets[b];
  float corr = 0.f;
  u16x8 qv = ((const u16x8*)(qb + (size_t)b * D_))[lane];
  for (int ii = w; ii <= F_; ii += 8) {
    if (!uq[ii]) continue;                       // wave-uniform branch
    int p = idx[ii];
    u16x8 rv = ((const u16x8*)(rt + (size_t)p * D_))[lane];
    float s = 0.f;
#pragma unroll
    for (int j = 0; j < 8; ++j) s += bf2f(qv[j]) * bf2f(rv[j]);
    for (int off = 32; off; off >>= 1) s += __shfl_down(s, off, 64);
    if (lane == 0)
      corr += (NEGV >= t ? 1.f : 0.f) - (s >= t ? 1.f : 0.f);
  }
  if (lane == 0 && corr != 0.f) atomicAdd(&out[b], corr);
}

// ---- fallback path (ws too small) ------------------------------------------
__global__ void targets_init(const float* __restrict__ q, const float* __restrict__ rhs,
                             const int* __restrict__ queries, float* __restrict__ targets,
                             float* __restrict__ out) {
  __shared__ float wsum[4];
  int b = blockIdx.x;
  int tid = threadIdx.x, lane = tid & 63, w = tid >> 6;
  int p = queries[b * 3 + 2];
  float s = 0.f;
  for (int d = tid; d < D_; d += 256) s += q[b * D_ + d] * rhs[(size_t)d * N_ + p];
  for (int off = 32; off; off >>= 1) s += __shfl_down(s, off, 64);
  if (lane == 0) wsum[w] = s;
  __syncthreads();
  if (tid == 0) {
    targets[b] = wsum[0] + wsum[1] + wsum[2] + wsum[3];
    out[b] = 1.0f;
  }
}

__global__ void fallback_count(const float* __restrict__ q, const float* __restrict__ rhs,
                               const int* __restrict__ queries, const int* __restrict__ filt,
                               const float* __restrict__ targets, float* __restrict__ out) {
  int b = blockIdx.y;
  int n = blockIdx.x * 256 + threadIdx.x;
  __shared__ float qs[D_];
  __shared__ int idx[F_ + 1];
  __shared__ int cnt;
  for (int d = threadIdx.x; d < D_; d += 256) qs[d] = q[b * D_ + d];
  if (threadIdx.x < F_) idx[threadIdx.x] = filt[b * F_ + threadIdx.x];
  if (threadIdx.x == F_) idx[F_] = queries[b * 3 + 2];
  if (threadIdx.x == 0) cnt = 0;
  __syncthreads();
  if (n < N_) {
    float t = targets[b];
    float s = 0.f;
    for (int d = 0; d < D_; ++d) s += qs[d] * rhs[(size_t)d * N_ + n];
    bool member = false;
    for (int j = 0; j <= F_; ++j)
      if (idx[j] == n) member = true;
    float sv = member ? NEGV : s;
    if (sv >= t) atomicAdd(&cnt, 1);
  }
  __syncthreads();
  if (threadIdx.x == 0 && cnt) atomicAdd(&out[b], (float)cnt);
}

extern "C" void kernel_launch(void* const* d_in, const int* in_sizes, int n_in,
                              void* d_out, int out_size, void* d_ws, size_t ws_size,
                              hipStream_t stream) {
  const float* q = (const float*)d_in[0];
  const float* rhs = (const float*)d_in[1];
  const int* queries = (const int*)d_in[2];
  const int* filt = (const int*)d_in[3];
  float* out = (float*)d_out;

  char* wsb = (char*)d_ws;
  float* targets = (float*)wsb;                                   // 8 KB
  unsigned short* qb = (unsigned short*)(wsb + 8192);             // 2 MB
  unsigned short* rt = (unsigned short*)(wsb + 8192 + (size_t)B_ * D_ * 2);  // 102.4 MB
  size_t need = 8192 + (size_t)B_ * D_ * 2 + (size_t)N_ * D_ * 2;

  if (ws_size >= need) {
    targets_convert<<<B_, 256, 0, stream>>>(q, rhs, queries, targets, out, qb);
    transpose_rhs<<<dim3((N_ + 63) / 64, D_ / 64), 256, 0, stream>>>(rhs, rt);
    gemm_count<<<GRID, 256, 0, stream>>>(qb, rt, targets, out);
    corrections<<<B_, 512, 0, stream>>>(qb, rt, queries, filt, targets, out);
  } else {
    targets_init<<<B_, 256, 0, stream>>>(q, rhs, queries, targets, out);
    fallback_count<<<dim3((N_ + 255) / 256, B_), 256, 0, stream>>>(q, rhs, queries, filt, targets, out);
  }
}

// Round 3
// 599.440 us; speedup vs baseline: 1.0934x; 1.0934x over previous
//
#include <hip/hip_runtime.h>
#include <hip/hip_bf16.h>

#define B_ 2048
#define D_ 512
#define N_ 100000
#define F_ 64
#define NEGV (-1000000.0f)

#define GEMM_BLKS 12512   // 16 m-tiles x 782 n-tiles (128x128), = 8 * 1564
#define TR_BLKS 12504     // 1563 n-chunks x 8 d-chunks

typedef __bf16 bfx8 __attribute__((ext_vector_type(8)));
typedef float f32x4 __attribute__((ext_vector_type(4)));
typedef unsigned short u16x8 __attribute__((ext_vector_type(8)));

static __device__ __forceinline__ unsigned short f2bf(float f) {
  unsigned u = __float_as_uint(f);
  unsigned r = (u + 0x7fffu + ((u >> 16) & 1u)) >> 16;
  return (unsigned short)r;
}
static __device__ __forceinline__ float bf2f(unsigned short u) {
  return __uint_as_float(((unsigned)u) << 16);
}

static __device__ __forceinline__ void async_copy16(const void* g, void* l) {
  __builtin_amdgcn_global_load_lds((const __attribute__((address_space(1))) void*)g,
                                   (__attribute__((address_space(3))) void*)l, 16, 0, 0);
}

// ---- prep: fused targets_convert (blocks 0..2047) + transpose (rest) -------
// targets blocks are latency-bound gathers; transpose blocks are BW-bound.
// Fusing overlaps them and drops one dispatch.
__global__ void prep(const float* __restrict__ q, const float* __restrict__ rhs,
                     const int* __restrict__ queries, float* __restrict__ targets,
                     float* __restrict__ out, unsigned short* __restrict__ qb,
                     unsigned short* __restrict__ rt) {
  __shared__ float tile[64][65];
  __shared__ float wsum[4];
  int tid = threadIdx.x;

  if (blockIdx.x < B_) {
    // ---- targets (fp32, matches reference einsum) + out init + q->bf16 ----
    int b = blockIdx.x;
    int lane = tid & 63, w = tid >> 6;
    int p = queries[b * 3 + 2];
    float2 v = ((const float2*)(q + (size_t)b * D_))[tid];   // 256 x 2 = 512
    ushort2 o; o.x = f2bf(v.x); o.y = f2bf(v.y);
    ((ushort2*)(qb + (size_t)b * D_))[tid] = o;
    float s = v.x * rhs[(size_t)(2 * tid) * N_ + p] + v.y * rhs[(size_t)(2 * tid + 1) * N_ + p];
    for (int off = 32; off; off >>= 1) s += __shfl_down(s, off, 64);
    if (lane == 0) wsum[w] = s;
    __syncthreads();
    if (tid == 0) {
      targets[b] = wsum[0] + wsum[1] + wsum[2] + wsum[3];
      out[b] = 1.0f;
    }
    return;
  }

  // ---- rhs (D x N fp32) -> rt (N x D bf16), 64x64 LDS tile transpose ------
  int t = blockIdx.x - B_;
  int n0 = (t >> 3) * 64, d0 = (t & 7) * 64;   // d-major: 8 blocks complete rt rows
  if (n0 + 64 <= N_) {
#pragma unroll
    for (int p = 0; p < 4; ++p) {
      int e = p * 256 + tid;
      int d = e >> 4, c4 = e & 15;
      float4 v = *(const float4*)(rhs + (size_t)(d0 + d) * N_ + n0 + c4 * 4);
      tile[d][c4 * 4 + 0] = v.x; tile[d][c4 * 4 + 1] = v.y;
      tile[d][c4 * 4 + 2] = v.z; tile[d][c4 * 4 + 3] = v.w;
    }
  } else {
    int c = tid & 63, r4 = tid >> 6;
#pragma unroll
    for (int p = 0; p < 16; ++p) {
      int d = r4 + p * 4;
      if (n0 + c < N_) tile[d][c] = rhs[(size_t)(d0 + d) * N_ + n0 + c];
    }
  }
  __syncthreads();
#pragma unroll
  for (int p = 0; p < 4; ++p) {
    int e = p * 256 + tid;
    int n = e >> 4, dg = e & 15;
    if (n0 + n < N_) {
      ushort4 o;
      o.x = f2bf(tile[dg * 4 + 0][n]);
      o.y = f2bf(tile[dg * 4 + 1][n]);
      o.z = f2bf(tile[dg * 4 + 2][n]);
      o.w = f2bf(tile[dg * 4 + 3][n]);
      *(ushort4*)(rt + (size_t)(n0 + n) * D_ + d0 + dg * 4) = o;
    }
  }
}

// ---- main: round-0 proven structure (128x128, BK=32, 2-buf, free-running ---
// 3-4 blocks/CU) + zero-conflict LDS swizzle (r2-proven) + bijective XCD
// chunking + corrections fused as 2048 leading blocks (atomicAdd-commutes).
// Swizzle: 16B granule g of row m stored at physical g ^ ((m>>1)&3); staged
// via pre-swizzled GLOBAL source + linear LDS dest (global_load_lds rule).
__global__ void __launch_bounds__(256) gemm_corr(
    const unsigned short* __restrict__ qb,   // B x D bf16
    const unsigned short* __restrict__ rt,   // N x D bf16 (transposed rhs)
    const int* __restrict__ queries,
    const int* __restrict__ filt,
    const float* __restrict__ targets,
    float* __restrict__ out) {
  __shared__ unsigned short As[2][128 * 32];   // 2 x 8 KB
  __shared__ unsigned short Bs[2][128 * 32];
  __shared__ float sT[128];
  __shared__ int cnt2[2][128];
  __shared__ int idx[F_ + 1];
  __shared__ unsigned char uq[F_ + 1];

  int tid = threadIdx.x;
  int w = tid >> 6, lane = tid & 63;

  if (blockIdx.x < B_) {
    // ---- corrections: wave-cooperative dots over filter ∪ {true}, 4 waves --
    int b = blockIdx.x;
    if (tid <= F_) idx[tid] = (tid < F_) ? filt[b * F_ + tid] : queries[b * 3 + 2];
    __syncthreads();
    if (tid <= F_) {
      int p = idx[tid];
      bool u = true;
      for (int j = 0; j < tid; ++j)
        if (idx[j] == p) u = false;
      uq[tid] = u;
    }
    __syncthreads();
    float t = targets[b];
    float corr = 0.f;
    u16x8 qv = ((const u16x8*)(qb + (size_t)b * D_))[lane];
    for (int ii = w; ii <= F_; ii += 4) {
      if (!uq[ii]) continue;                   // wave-uniform branch
      int p = idx[ii];
      u16x8 rv = ((const u16x8*)(rt + (size_t)p * D_))[lane];
      float s = 0.f;
#pragma unroll
      for (int j = 0; j < 8; ++j) s += bf2f(qv[j]) * bf2f(rv[j]);
      for (int off = 32; off; off >>= 1) s += __shfl_down(s, off, 64);
      if (lane == 0)
        corr += (NEGV >= t ? 1.f : 0.f) - (s >= t ? 1.f : 0.f);
    }
    if (lane == 0 && corr != 0.f) atomicAdd(&out[b], corr);
    return;
  }

  // ---- GEMM-count body ------------------------------------------------------
  int g = blockIdx.x - B_;
  // bijective XCD chunking: HW XCD = blockIdx%8 = g%8 (B_%8==0). Each XCD gets
  // one contiguous lin chunk, m-major: 16 consecutive lin share an n-panel.
  int lin = (g & 7) * (GEMM_BLKS / 8) + (g >> 3);
  int m0 = (lin & 15) * 128;
  int n0 = (lin >> 4) * 128;

  if (tid < 128) sT[tid] = targets[m0 + tid];

  int mw = (w & 1) * 64, nw = (w >> 1) * 64;
  int quad = lane >> 4, l16 = lane & 15;
  // swizzled in-row 16B-granule offset for fragment reads (zero-conflict, r2)
  int xg = (quad ^ ((l16 >> 1) & 3)) * 8;

  // per-thread staging coordinates (2 chunks of 16B per matrix per kt);
  // source column pre-swizzled so linear LDS dest holds the swizzled layout
  int c0 = tid, c1 = 256 + tid;
  int am0 = c0 >> 2, am1 = c1 >> 2;
  int aj0 = ((c0 & 3) ^ ((c0 >> 3) & 3)) * 8;
  int aj1 = ((c1 & 3) ^ ((c1 >> 3) & 3)) * 8;
  int bn0g = n0 + am0; if (bn0g > N_ - 1) bn0g = N_ - 1;
  int bn1g = n0 + am1; if (bn1g > N_ - 1) bn1g = N_ - 1;
  const unsigned short* agp0 = qb + (size_t)(m0 + am0) * D_ + aj0;
  const unsigned short* agp1 = qb + (size_t)(m0 + am1) * D_ + aj1;
  const unsigned short* bgp0 = rt + (size_t)bn0g * D_ + aj0;
  const unsigned short* bgp1 = rt + (size_t)bn1g * D_ + aj1;

  f32x4 acc[4][4];
  f32x4 z = {0.f, 0.f, 0.f, 0.f};
#pragma unroll
  for (int i = 0; i < 4; ++i)
#pragma unroll
    for (int j = 0; j < 4; ++j) acc[i][j] = z;

  // prologue: stage kt=0 into buffer 0
  async_copy16(agp0, &As[0][c0 * 8]);
  async_copy16(agp1, &As[0][c1 * 8]);
  async_copy16(bgp0, &Bs[0][c0 * 8]);
  async_copy16(bgp1, &Bs[0][c1 * 8]);

  for (int kt = 0; kt < 16; ++kt) {
    int buf = kt & 1;
    __syncthreads();                    // drains kt's copies; frees other buffer
    if (kt + 1 < 16) {
      int nb = 1 - buf, k1 = (kt + 1) * 32;
      async_copy16(agp0 + k1, &As[nb][c0 * 8]);
      async_copy16(agp1 + k1, &As[nb][c1 * 8]);
      async_copy16(bgp0 + k1, &Bs[nb][c0 * 8]);
      async_copy16(bgp1 + k1, &Bs[nb][c1 * 8]);
    }

    bfx8 a[4], b[4];
#pragma unroll
    for (int mi = 0; mi < 4; ++mi) {
      int m = mw + mi * 16 + l16;
      u16x8 au = *(const u16x8*)(&As[buf][m * 32 + xg]);
      a[mi] = __builtin_bit_cast(bfx8, au);
    }
#pragma unroll
    for (int ni = 0; ni < 4; ++ni) {
      int n = nw + ni * 16 + l16;
      u16x8 bu = *(const u16x8*)(&Bs[buf][n * 32 + xg]);
      b[ni] = __builtin_bit_cast(bfx8, bu);
    }
#pragma unroll
    for (int mi = 0; mi < 4; ++mi)
#pragma unroll
      for (int ni = 0; ni < 4; ++ni)
        acc[mi][ni] = __builtin_amdgcn_mfma_f32_16x16x32_bf16(a[mi], b[ni], acc[mi][ni], 0, 0, 0);
  }

  // epilogue: compare vs target, quad shuffle-reduce, conflict-free stores
#pragma unroll
  for (int mi = 0; mi < 4; ++mi) {
#pragma unroll
    for (int reg = 0; reg < 4; ++reg) {
      int rl = mw + mi * 16 + quad * 4 + reg;   // C/D: row=(lane>>4)*4+reg
      float t = sT[rl];
      int c = 0;
#pragma unroll
      for (int ni = 0; ni < 4; ++ni) {
        int col = n0 + nw + ni * 16 + l16;      // C/D: col=lane&15
        if (col < N_ && acc[mi][ni][reg] >= t) c++;
      }
      c += __shfl_xor(c, 1, 64);
      c += __shfl_xor(c, 2, 64);
      c += __shfl_xor(c, 4, 64);
      c += __shfl_xor(c, 8, 64);
      if (l16 == 0) cnt2[w >> 1][rl] = c;       // each slot written exactly once
    }
  }
  __syncthreads();
  if (tid < 128) {
    int tot = cnt2[0][tid] + cnt2[1][tid];
    if (tot) atomicAdd(&out[m0 + tid], (float)tot);
  }
}

// ---- fallback path (ws too small) ------------------------------------------
__global__ void targets_init(const float* __restrict__ q, const float* __restrict__ rhs,
                             const int* __restrict__ queries, float* __restrict__ targets,
                             float* __restrict__ out) {
  __shared__ float wsum[4];
  int b = blockIdx.x;
  int tid = threadIdx.x, lane = tid & 63, w = tid >> 6;
  int p = queries[b * 3 + 2];
  float s = 0.f;
  for (int d = tid; d < D_; d += 256) s += q[b * D_ + d] * rhs[(size_t)d * N_ + p];
  for (int off = 32; off; off >>= 1) s += __shfl_down(s, off, 64);
  if (lane == 0) wsum[w] = s;
  __syncthreads();
  if (tid == 0) {
    targets[b] = wsum[0] + wsum[1] + wsum[2] + wsum[3];
    out[b] = 1.0f;
  }
}

__global__ void fallback_count(const float* __restrict__ q, const float* __restrict__ rhs,
                               const int* __restrict__ queries, const int* __restrict__ filt,
                               const float* __restrict__ targets, float* __restrict__ out) {
  int b = blockIdx.y;
  int n = blockIdx.x * 256 + threadIdx.x;
  __shared__ float qs[D_];
  __shared__ int idx[F_ + 1];
  __shared__ int cnt;
  for (int d = threadIdx.x; d < D_; d += 256) qs[d] = q[b * D_ + d];
  if (threadIdx.x < F_) idx[threadIdx.x] = filt[b * F_ + threadIdx.x];
  if (threadIdx.x == F_) idx[F_] = queries[b * 3 + 2];
  if (threadIdx.x == 0) cnt = 0;
  __syncthreads();
  if (n < N_) {
    float t = targets[b];
    float s = 0.f;
    for (int d = 0; d < D_; ++d) s += qs[d] * rhs[(size_t)d * N_ + n];
    bool member = false;
    for (int j = 0; j <= F_; ++j)
      if (idx[j] == n) member = true;
    float sv = member ? NEGV : s;
    if (sv >= t) atomicAdd(&cnt, 1);
  }
  __syncthreads();
  if (threadIdx.x == 0 && cnt) atomicAdd(&out[b], (float)cnt);
}

extern "C" void kernel_launch(void* const* d_in, const int* in_sizes, int n_in,
                              void* d_out, int out_size, void* d_ws, size_t ws_size,
                              hipStream_t stream) {
  const float* q = (const float*)d_in[0];
  const float* rhs = (const float*)d_in[1];
  const int* queries = (const int*)d_in[2];
  const int* filt = (const int*)d_in[3];
  float* out = (float*)d_out;

  char* wsb = (char*)d_ws;
  float* targets = (float*)wsb;                                   // 8 KB
  unsigned short* qb = (unsigned short*)(wsb + 8192);             // 2 MB
  unsigned short* rt = (unsigned short*)(wsb + 8192 + (size_t)B_ * D_ * 2);  // 102.4 MB
  size_t need = 8192 + (size_t)B_ * D_ * 2 + (size_t)N_ * D_ * 2;

  if (ws_size >= need) {
    prep<<<B_ + TR_BLKS, 256, 0, stream>>>(q, rhs, queries, targets, out, qb, rt);
    gemm_corr<<<B_ + GEMM_BLKS, 256, 0, stream>>>(qb, rt, queries, filt, targets, out);
  } else {
    targets_init<<<B_, 256, 0, stream>>>(q, rhs, queries, targets, out);
    fallback_count<<<dim3((N_ + 255) / 256, B_), 256, 0, stream>>>(q, rhs, queries, filt, targets, out);
  }
}